// Round 4
// baseline (627.914 us; speedup 1.0000x reference)
//
#include <hip/hip_runtime.h>
#include <hip/hip_bf16.h>
#include <cstdint>

#define NN 256
#define NB 4
#define OC 128

using bf16x8_t = __attribute__((ext_vector_type(8))) __bf16;
using f32x4_t  = __attribute__((ext_vector_type(4))) float;

typedef const __attribute__((address_space(1))) uint8_t* gptr1_t;
typedef __attribute__((address_space(3))) uint8_t* lptr3_t;

__device__ __forceinline__ void async_load16(const void* g, void* l) {
  __builtin_amdgcn_global_load_lds((gptr1_t)g, (lptr3_t)l, 16, 0, 0);
}

__device__ __forceinline__ float sigf(float x) {
  return 1.0f / (1.0f + __expf(-x));
}

__device__ __forceinline__ uint16_t f2bf_rne(float f) {
  uint32_t u = __float_as_uint(f);
  uint32_t r = (u + 0x7fffu + ((u >> 16) & 1u)) >> 16;
  return (uint16_t)r;
}

// ---------------------------------------------------------------------------
// prep: bf16 Wt[n][k] (gemm2 B), Bt[n][k] (small-GEMM B = [W1|Wa|Wc]),
// g1bf0 static slots (f0/f1/pad), r2b/r2c init (max=0,min=1), counters zero.
// ---------------------------------------------------------------------------
__device__ __forceinline__ void emit_wt(const float* __restrict__ W2,
                                        uint16_t* __restrict__ Wt, int d1,
                                        int d2, int idx) {
  const int K = 2 * d2;
  const int nn = idx / K, k = idx - nn * K;
  const int row = (k < d2) ? (d1 + k) : (2 * d1 + d2 + (k - d2));
  Wt[idx] = f2bf_rne(W2[row * OC + nn]);
}

__device__ __forceinline__ void emit_bt(const float* __restrict__ W1,
                                        const float* __restrict__ W2, uint16_t* __restrict__ Bt,
                                        int D0, int D1, int D2, int FIN1,
                                        int KP, int idx) {
  const int n = idx / KP, k = idx - n * KP;
  float val = 0.f;
  if (n < 128) {
    if (k < FIN1) val = W1[k * OC + n];
  } else if (n < 256) {
    if (k >= D0 && k < D0 + D1) val = W2[(k - D0) * OC + (n - 128)];
  } else {
    if (k >= D0 && k < D0 + D1) val = W2[(D1 + D2 + (k - D0)) * OC + (n - 256)];
  }
  Bt[idx] = f2bf_rne(val);
}

__global__ __launch_bounds__(256) void prep_all(
    const float* __restrict__ W2_0, const float* __restrict__ W2_1,
    const float* __restrict__ W2_2, const float* __restrict__ W1_0,
    const float* __restrict__ W1_1, const float* __restrict__ W1_2,
    const float* __restrict__ x0, const float* __restrict__ x1,
    uint16_t* __restrict__ Wt0, uint16_t* __restrict__ Wt1,
    uint16_t* __restrict__ Wt2, uint16_t* __restrict__ Bt0,
    uint16_t* __restrict__ Bt1, uint16_t* __restrict__ Bt2,
    uint16_t* __restrict__ g1bf0, float* __restrict__ r2b,
    float* __restrict__ r2c, unsigned* __restrict__ cnt) {
  int g = blockIdx.x * 256 + threadIdx.x;
  if (g < 16384) { emit_wt(W2_0, Wt0, 64, 64, g); return; }
  g -= 16384;
  if (g < 32768) { emit_wt(W2_1, Wt1, 128, 128, g); return; }
  g -= 32768;
  if (g < 32768) { emit_wt(W2_2, Wt2, 128, 128, g); return; }
  g -= 32768;
  if (g < 98304) { emit_bt(W1_0, W2_0, Bt0, 32, 64, 64, 224, 256, g); return; }
  g -= 98304;
  if (g < 196608) { emit_bt(W1_1, W2_1, Bt1, 128, 128, 128, 512, 512, g); return; }
  g -= 196608;
  if (g < 196608) { emit_bt(W1_2, W2_2, Bt2, 128, 128, 128, 512, 512, g); return; }
  g -= 196608;
  if (g < 131072) {  // g1bf0 static slots: f0[0..32) f1[32..96) pad[224..256)
    const int row = g >> 7, t = g & 127;
    uint16_t* const gp = g1bf0 + (size_t)row * 256;
    if (t < 32) gp[t] = f2bf_rne(x0[(row >> 8) * 32 + t]);
    else if (t < 96) gp[t] = f2bf_rne(x1[(size_t)row * 64 + (t - 32)]);
    else gp[128 + t] = 0;
    return;
  }
  g -= 131072;
  if (g < 262144) { r2b[g] = ((g & 255) < 128) ? 0.f : 1.f; return; }
  g -= 262144;
  if (g < 262144) { r2c[g] = ((g & 255) < 128) ? 0.f : 1.f; return; }
  g -= 262144;
  if (g < 2048) cnt[g] = 0u;
}

// ---------------------------------------------------------------------------
// reduce2 layer 0: fp32 x2 [B,n,n,64] -> bf16 x2bf (gemm2 A operand) + bf16
// max/min into g1bf0 r2-slot [96..224). Unroll x2 with dual accumulators.
// ---------------------------------------------------------------------------
__global__ __launch_bounds__(256) void reduce2_l0_kernel(
    const float* __restrict__ x2, uint16_t* __restrict__ g1bf0,
    uint16_t* __restrict__ x2bf) {
  const int bid = blockIdx.x;            // b*256 + i
  const int i = bid & 255;
  const int tid = threadIdx.x;
  const int q = tid & 15, s = tid >> 4;  // 16 quads, 16 stripes
  const size_t rowbase = ((size_t)bid * NN) * 64 + q * 4;
  float mxA0 = 0.f, mxA1 = 0.f, mxA2 = 0.f, mxA3 = 0.f;
  float mnA0 = 1.f, mnA1 = 1.f, mnA2 = 1.f, mnA3 = 1.f;
  float mxB0 = 0.f, mxB1 = 0.f, mxB2 = 0.f, mxB3 = 0.f;
  float mnB0 = 1.f, mnB1 = 1.f, mnB2 = 1.f, mnB3 = 1.f;
#pragma unroll 2
  for (int t = 0; t < 16; t += 2) {
    const int jA = s + t * 16, jB = jA + 16;
    const float4 xa = *(const float4*)(x2 + rowbase + (size_t)jA * 64);
    const float4 xb = *(const float4*)(x2 + rowbase + (size_t)jB * 64);
    uint2 pa, pb;
    pa.x = (uint32_t)f2bf_rne(xa.x) | ((uint32_t)f2bf_rne(xa.y) << 16);
    pa.y = (uint32_t)f2bf_rne(xa.z) | ((uint32_t)f2bf_rne(xa.w) << 16);
    pb.x = (uint32_t)f2bf_rne(xb.x) | ((uint32_t)f2bf_rne(xb.y) << 16);
    pb.y = (uint32_t)f2bf_rne(xb.z) | ((uint32_t)f2bf_rne(xb.w) << 16);
    *(uint2*)(x2bf + rowbase + (size_t)jA * 64) = pa;
    *(uint2*)(x2bf + rowbase + (size_t)jB * 64) = pb;
    if (jA != i) {
      mxA0 = fmaxf(mxA0, xa.x); mxA1 = fmaxf(mxA1, xa.y);
      mxA2 = fmaxf(mxA2, xa.z); mxA3 = fmaxf(mxA3, xa.w);
      mnA0 = fminf(mnA0, xa.x); mnA1 = fminf(mnA1, xa.y);
      mnA2 = fminf(mnA2, xa.z); mnA3 = fminf(mnA3, xa.w);
    }
    if (jB != i) {
      mxB0 = fmaxf(mxB0, xb.x); mxB1 = fmaxf(mxB1, xb.y);
      mxB2 = fmaxf(mxB2, xb.z); mxB3 = fmaxf(mxB3, xb.w);
      mnB0 = fminf(mnB0, xb.x); mnB1 = fminf(mnB1, xb.y);
      mnB2 = fminf(mnB2, xb.z); mnB3 = fminf(mnB3, xb.w);
    }
  }
  float mx0 = fmaxf(mxA0, mxB0), mx1 = fmaxf(mxA1, mxB1);
  float mx2 = fmaxf(mxA2, mxB2), mx3 = fmaxf(mxA3, mxB3);
  float mn0 = fminf(mnA0, mnB0), mn1 = fminf(mnA1, mnB1);
  float mn2 = fminf(mnA2, mnB2), mn3 = fminf(mnA3, mnB3);
  __shared__ float4 smx[256], smn[256];
  smx[tid] = make_float4(mx0, mx1, mx2, mx3);
  smn[tid] = make_float4(mn0, mn1, mn2, mn3);
  __syncthreads();
  if (s == 0) {
    for (int ss = 1; ss < 16; ++ss) {
      float4 a = smx[q + ss * 16], c = smn[q + ss * 16];
      mx0 = fmaxf(mx0, a.x); mx1 = fmaxf(mx1, a.y);
      mx2 = fmaxf(mx2, a.z); mx3 = fmaxf(mx3, a.w);
      mn0 = fminf(mn0, c.x); mn1 = fminf(mn1, c.y);
      mn2 = fminf(mn2, c.z); mn3 = fminf(mn3, c.w);
    }
    uint16_t* const g = g1bf0 + (size_t)bid * 256;
    g[96 + q * 4 + 0] = f2bf_rne(mx0); g[96 + q * 4 + 1] = f2bf_rne(mx1);
    g[96 + q * 4 + 2] = f2bf_rne(mx2); g[96 + q * 4 + 3] = f2bf_rne(mx3);
    g[160 + q * 4 + 0] = f2bf_rne(mn0); g[160 + q * 4 + 1] = f2bf_rne(mn1);
    g[160 + q * 4 + 2] = f2bf_rne(mn2); g[160 + q * 4 + 3] = f2bf_rne(mn3);
  }
}

// ---------------------------------------------------------------------------
// Small fused MFMA GEMM + o0. Blocks 0..47: C[1024 x 384] = g1 @ Bt^T
// (nt=0 -> f1out=sigmoid(+b1) [+bf16 dup], nt=1 -> u=+b2, nt=2 -> v).
// Blocks 48..51: o0 for batch b = bid-48:
//   f0out = sigmoid([f0, max_i f1, min_i f1] @ W0 + b0)  [+bf16 bcast dup]
// ---------------------------------------------------------------------------
template <int KP, int D0, int D1, bool DUP>
__global__ __launch_bounds__(256) void small_gemm(
    const uint16_t* __restrict__ g1, const uint16_t* __restrict__ Bt,
    const float* __restrict__ b1, const float* __restrict__ b2,
    float* __restrict__ f1out, uint16_t* __restrict__ g1next,
    float* __restrict__ u, float* __restrict__ v,
    const float* __restrict__ f0in, const float* __restrict__ f1in,
    const float* __restrict__ W0, const float* __restrict__ b0,
    float* __restrict__ f0out) {
  constexpr int NCH = KP / 64;
  const int bid = blockIdx.x;
  const int tid = threadIdx.x;

  __shared__ __align__(16) uint8_t ldsA[8192];
  __shared__ __align__(16) uint8_t ldsB[16384];

  if (bid < 48) {
    const int mt = bid / 3, nt = bid - mt * 3;
    const int m0 = mt * 64, n0 = nt * 128;
    const int wv = tid >> 6, lane = tid & 63;
    const int l15 = lane & 15, l4 = lane >> 4;

    f32x4_t acc[4][2];
#pragma unroll
    for (int a = 0; a < 4; ++a)
#pragma unroll
      for (int q = 0; q < 2; ++q) acc[a][q] = (f32x4_t){0.f, 0.f, 0.f, 0.f};

    for (int c = 0; c < NCH; ++c) {
      const int kbg = c * 64;
#pragma unroll
      for (int t = 0; t < 2; ++t) {  // A units: id = ks*4 + mi
        const int id = wv * 2 + t;
        const int mi = id & 3, ks = id >> 2;
        async_load16(g1 + (size_t)(m0 + mi * 16 + l15) * KP + kbg + ks * 32 + l4 * 8,
                     ldsA + id * 1024);
      }
#pragma unroll
      for (int t = 0; t < 4; ++t) {  // B units: id = ks*8 + ni
        const int id = wv * 4 + t;
        const int ni = id & 7, ks = id >> 3;
        async_load16(Bt + (size_t)(n0 + ni * 16 + l15) * KP + kbg + ks * 32 + l4 * 8,
                     ldsB + id * 1024);
      }
      __syncthreads();
#pragma unroll
      for (int ks = 0; ks < 2; ++ks) {
        bf16x8_t Af[4], Bf[2];
#pragma unroll
        for (int a = 0; a < 4; ++a)
          Af[a] = *(const bf16x8_t*)(ldsA + ((ks * 4 + a) << 10) + (lane << 4));
#pragma unroll
        for (int q = 0; q < 2; ++q)
          Bf[q] = *(const bf16x8_t*)(ldsB + ((ks * 8 + wv * 2 + q) << 10) + (lane << 4));
#pragma unroll
        for (int a = 0; a < 4; ++a)
#pragma unroll
          for (int q = 0; q < 2; ++q)
            acc[a][q] = __builtin_amdgcn_mfma_f32_16x16x32_bf16(Af[a], Bf[q],
                                                                acc[a][q], 0, 0, 0);
      }
      __syncthreads();
    }

    float bias[2];
#pragma unroll
    for (int q = 0; q < 2; ++q) {
      const int cc = wv * 32 + q * 16 + l15;
      bias[q] = (nt == 0) ? b1[cc] : ((nt == 1) ? b2[cc] : 0.f);
    }
#pragma unroll
    for (int a = 0; a < 4; ++a) {
      const int rl = a * 16 + l4 * 4;
#pragma unroll
      for (int r = 0; r < 4; ++r) {
        const size_t bi = m0 + rl + r;
#pragma unroll
        for (int q = 0; q < 2; ++q) {
          const int cc = wv * 32 + q * 16 + l15;
          const float x = acc[a][q][r] + bias[q];
          if (nt == 0) {
            const float val = sigf(x);
            f1out[bi * OC + cc] = val;
            if (DUP) g1next[bi * 512 + 128 + cc] = f2bf_rne(val);
          } else if (nt == 1) {
            u[bi * OC + cc] = x;
          } else {
            v[bi * OC + cc] = x;
          }
        }
      }
    }
  } else {
    // ---- o0 for batch b ----
    constexpr int FIN0 = D0 + 2 * D1;
    constexpr int S = 256 / D1;
    const int b = bid - 48;
    float* const sm = (float*)ldsA;   // reuse LDS: g0 | smx | smn | sval
    float* const g0 = sm;             // [0..FIN0)
    float* const smx = sm + 512;      // [512..768)
    float* const smn = sm + 768;      // [768..1024)
    float* const sval = sm + 1024;    // [1024..1152)
    const int cc = tid & (D1 - 1), ss = tid / D1;
    float mx = -1e30f, mn = 1e30f;
    const float* f1b = f1in + (size_t)b * NN * D1;
    for (int j = ss; j < NN; j += S) {
      const float x = f1b[(size_t)j * D1 + cc];
      mx = fmaxf(mx, x); mn = fminf(mn, x);
    }
    smx[tid] = mx; smn[tid] = mn;
    __syncthreads();
    if (ss == 0) {
      for (int s2 = 1; s2 < S; ++s2) {
        mx = fmaxf(mx, smx[cc + s2 * D1]);
        mn = fminf(mn, smn[cc + s2 * D1]);
      }
      g0[D0 + cc] = mx;
      g0[D0 + D1 + cc] = mn;
    }
    if (tid < D0) g0[tid] = f0in[b * D0 + tid];
    __syncthreads();
    if (tid < OC) {
      float acc = b0[tid];
#pragma unroll 8
      for (int k = 0; k < FIN0; ++k) acc += g0[k] * W0[k * OC + tid];
      const float val = sigf(acc);
      f0out[b * OC + tid] = val;
      sval[tid] = val;
    }
    if (DUP) {
      __syncthreads();
      for (int idx = tid; idx < 256 * 128; idx += 256) {
        const int row = idx >> 7, c2 = idx & 127;
        g1next[((size_t)(b * 256 + row)) * 512 + c2] = f2bf_rne(sval[c2]);
      }
    }
  }
}

// ---------------------------------------------------------------------------
// Big order-2 GEMM. Block = (b, i, j-tile of 128): output 128 rows x 128 ch.
//   acc[j,c] = sum_k f2[b,i,j,k]*Wb[k,c] + sum_k f2[b,j,i,k]*Wd[k,c]
//   out = sigmoid(acc + u[b,i,c] + v[b,j,c])
// bf16-out path: LDS-staged coalesced stores + fused next-layer reduce2
// (device atomics, exclude j==i) + last-of-2-blocks fp32->bf16 r2 convert
// into g1next (counter-based; the 2 jt-blocks of (b,i) are the only writers).
// ---------------------------------------------------------------------------
template <int D2, typename OUT_T, bool REDUCE>
__global__ __launch_bounds__(256, 3) void gemm2_kernel(
    const __hip_bfloat16* __restrict__ f2, const uint16_t* __restrict__ Wt,
    const float* __restrict__ u, const float* __restrict__ v,
    OUT_T* __restrict__ out, float* __restrict__ r2n,
    unsigned* __restrict__ cnt, uint16_t* __restrict__ g1next) {
  constexpr int K = 2 * D2;
  constexpr int NCH = K / 64;
  constexpr bool BF16OUT = (sizeof(OUT_T) == 2);
  constexpr int LDSB = BF16OUT ? (128 * 272) : 32768;
  const int bid = blockIdx.x;
  const int jt = bid & 1, i = (bid >> 1) & 255, b = bid >> 9;
  const int j0 = jt * 128;
  const int tid = threadIdx.x;
  const int wv = tid >> 6, lane = tid & 63;
  const int wr = wv >> 1, wc = wv & 1;
  const int l15 = lane & 15, l4 = lane >> 4;

  __shared__ __align__(16) uint8_t lds[LDSB];
  __shared__ unsigned smax[128], smin[128];
  __shared__ unsigned sflag;
  uint8_t* const ldsA = lds;
  uint8_t* const ldsW = lds + 16384;

  const __hip_bfloat16* A1 = f2 + ((size_t)(b * NN + i) * NN + j0) * D2;
  const __hip_bfloat16* A2 = f2 + ((size_t)(b * NN + j0) * NN + i) * D2;

  f32x4_t acc[4][4];
#pragma unroll
  for (int a = 0; a < 4; ++a)
#pragma unroll
    for (int q = 0; q < 4; ++q) acc[a][q] = (f32x4_t){0.f, 0.f, 0.f, 0.f};

  for (int c = 0; c < NCH; ++c) {
    const int kbg = c * 64;
    const bool second = (kbg >= D2);
    const __hip_bfloat16* Ab = second ? A2 : A1;
    const size_t rstride = second ? (size_t)NN * D2 : (size_t)D2;
    const int kbase = second ? (kbg - D2) : kbg;
#pragma unroll
    for (int q = 0; q < 4; ++q) {
      const int id = wv * 4 + q;
      const int mi = id & 7, ks = id >> 3;
      const int row = mi * 16 + l15;
      const int kk = ks * 32 + l4 * 8;
      async_load16(Ab + (size_t)row * rstride + kbase + kk, ldsA + id * 1024);
    }
#pragma unroll
    for (int q = 0; q < 4; ++q) {
      const int id = wv * 4 + q;
      const int ni = id & 7, ks = id >> 3;
      const int nn2 = ni * 16 + l15;
      const int kk = ks * 32 + l4 * 8;
      async_load16(Wt + (size_t)nn2 * K + kbg + kk, ldsW + id * 1024);
    }
    __syncthreads();
#pragma unroll
    for (int ks = 0; ks < 2; ++ks) {
      bf16x8_t Af[4], Bf[4];
#pragma unroll
      for (int a = 0; a < 4; ++a)
        Af[a] = *(const bf16x8_t*)(ldsA + ((ks * 8 + wr * 4 + a) << 10) + (lane << 4));
#pragma unroll
      for (int q = 0; q < 4; ++q)
        Bf[q] = *(const bf16x8_t*)(ldsW + ((ks * 8 + wc * 4 + q) << 10) + (lane << 4));
#pragma unroll
      for (int a = 0; a < 4; ++a)
#pragma unroll
        for (int q = 0; q < 4; ++q)
          acc[a][q] = __builtin_amdgcn_mfma_f32_16x16x32_bf16(Af[a], Bf[q],
                                                              acc[a][q], 0, 0, 0);
    }
    __syncthreads();
  }

  const size_t bi2 = (size_t)(b * NN + i);
  float uval[4];
#pragma unroll
  for (int q = 0; q < 4; ++q) uval[q] = u[bi2 * OC + wc * 64 + q * 16 + l15];
  const size_t obase = (bi2 * NN + j0) * OC;
  const size_t vbase = (size_t)(b * NN + j0) * OC;

  if (BF16OUT) {
    if (REDUCE && tid < 128) { smax[tid] = 0u; smin[tid] = 0x3f800000u; }
    __syncthreads();
    float lmx[4] = {0.f, 0.f, 0.f, 0.f};
    float lmn[4] = {1.f, 1.f, 1.f, 1.f};
#pragma unroll
    for (int a = 0; a < 4; ++a) {
      const int rowb = wr * 64 + a * 16 + l4 * 4;
#pragma unroll
      for (int r = 0; r < 4; ++r) {
        const int j = rowb + r;
        const bool excl = (j0 + j) == i;
#pragma unroll
        for (int q = 0; q < 4; ++q) {
          const int col = wc * 64 + q * 16 + l15;
          const float x = acc[a][q][r] + uval[q] + v[vbase + (size_t)j * OC + col];
          const float sg = sigf(x);
          *(uint16_t*)(lds + j * 272 + col * 2) = f2bf_rne(sg);
          if (REDUCE && !excl) {
            lmx[q] = fmaxf(lmx[q], sg);
            lmn[q] = fminf(lmn[q], sg);
          }
        }
      }
    }
    if (REDUCE) {
#pragma unroll
      for (int q = 0; q < 4; ++q) {
        const int col = wc * 64 + q * 16 + l15;
        atomicMax(&smax[col], __float_as_uint(lmx[q]));
        atomicMin(&smin[col], __float_as_uint(lmn[q]));
      }
    }
    __syncthreads();
    uint16_t* const outp = (uint16_t*)out;
#pragma unroll
    for (int ci = 0; ci < 8; ++ci) {
      const int chunk = ci * 256 + tid;
      const int row = chunk >> 4, off = chunk & 15;
      const uint4 val = *(const uint4*)(lds + row * 272 + off * 16);
      *(uint4*)(outp + obase + (size_t)row * OC + off * 8) = val;
    }
    if (REDUCE) {
      unsigned* const r2u = (unsigned*)r2n;
      if (tid < 128) {
        atomicMax(&r2u[bi2 * 256 + tid], smax[tid]);
        atomicMin(&r2u[bi2 * 256 + 128 + tid], smin[tid]);
      }
      __syncthreads();  // all r2 atomics of this block issued & drained
      if (tid == 0) {
        __threadfence();
        sflag = (atomicAdd(&cnt[bi2], 1u) == 1u) ? 1u : 0u;
      }
      __syncthreads();
      if (sflag) {
        // both jt-blocks done: convert this row's r2 to bf16 into g1next
        const unsigned uv2 = atomicOr(&r2u[bi2 * 256 + tid], 0u);  // acquire read
        g1next[bi2 * 512 + 256 + tid] = f2bf_rne(__uint_as_float(uv2));
      }
    }
  } else {
    float* const outp = (float*)out;
#pragma unroll
    for (int a = 0; a < 4; ++a) {
      const int rowb = wr * 64 + a * 16 + l4 * 4;
#pragma unroll
      for (int r = 0; r < 4; ++r) {
        const int j = rowb + r;
#pragma unroll
        for (int q = 0; q < 4; ++q) {
          const int col = wc * 64 + q * 16 + l15;
          const float x = acc[a][q][r] + uval[q] + v[vbase + (size_t)j * OC + col];
          outp[obase + (size_t)j * OC + col] = sigf(x);
        }
      }
    }
  }
}

// ---------------------------------------------------------------------------
extern "C" void kernel_launch(void* const* d_in, const int* in_sizes, int n_in,
                              void* d_out, int out_size, void* d_ws,
                              size_t ws_size, hipStream_t stream) {
  const float* x0 = (const float*)d_in[0];
  const float* x1 = (const float*)d_in[1];
  const float* x2 = (const float*)d_in[2];
  const float *Wp[3][3], *bp[3][3];
  for (int l = 0; l < 3; ++l)
    for (int o = 0; o < 3; ++o) {
      Wp[l][o] = (const float*)d_in[3 + l * 6 + o * 2];
      bp[l][o] = (const float*)d_in[3 + l * 6 + o * 2 + 1];
    }

  const size_t F2E = (size_t)NB * NN * NN * OC;
  const size_t X2E = (size_t)NB * NN * NN * 64;

  uint8_t* ws = (uint8_t*)d_ws;
  size_t off = 0;
  auto carve = [&](size_t bytes) -> uint8_t* {
    uint8_t* p = ws + off;
    off += (bytes + 255) & ~(size_t)255;
    return p;
  };
  float* f0a = (float*)carve((size_t)NB * OC * 4);
  float* f0b = (float*)carve((size_t)NB * OC * 4);
  float* f1a = (float*)carve((size_t)NB * NN * OC * 4);
  float* f1b = (float*)carve((size_t)NB * NN * OC * 4);
  float* r2b = (float*)carve((size_t)NB * NN * 256 * 4);
  float* r2c = (float*)carve((size_t)NB * NN * 256 * 4);
  float* uu  = (float*)carve((size_t)NB * NN * OC * 4);
  float* vv  = (float*)carve((size_t)NB * NN * OC * 4);
  unsigned* cnt = (unsigned*)carve((size_t)2 * NB * NN * 4);
  unsigned* cnt1 = cnt;
  unsigned* cnt2 = cnt + NB * NN;
  uint16_t* Wt0 = (uint16_t*)carve((size_t)OC * 128 * 2);
  uint16_t* Wt1 = (uint16_t*)carve((size_t)OC * 256 * 2);
  uint16_t* Wt2 = (uint16_t*)carve((size_t)OC * 256 * 2);
  uint16_t* Bt0 = (uint16_t*)carve((size_t)384 * 256 * 2);
  uint16_t* Bt1 = (uint16_t*)carve((size_t)384 * 512 * 2);
  uint16_t* Bt2 = (uint16_t*)carve((size_t)384 * 512 * 2);
  uint16_t* g1bf0 = (uint16_t*)carve((size_t)NB * NN * 256 * 2);
  uint16_t* g1bf1 = (uint16_t*)carve((size_t)NB * NN * 512 * 2);
  uint16_t* g1bf2 = (uint16_t*)carve((size_t)NB * NN * 512 * 2);
  __hip_bfloat16* f2a = (__hip_bfloat16*)carve(F2E * 2);

  __hip_bfloat16* f2b;
  uint16_t* x2bf;
  if (ws_size >= off + F2E * 2) {
    f2b = (__hip_bfloat16*)carve(F2E * 2);
    x2bf = (uint16_t*)f2b;  // aliases f2b; dead before f2b becomes live
  } else {
    f2b = (__hip_bfloat16*)d_in[2];  // x2 fully consumed in layer 0
    x2bf = (uint16_t*)carve(X2E * 2);
  }

  float* out_f0 = (float*)d_out;
  float* out_f1 = out_f0 + (size_t)NB * OC;
  float* out_f2 = out_f1 + (size_t)NB * NN * OC;

  prep_all<<<4808, 256, 0, stream>>>(Wp[0][2], Wp[1][2], Wp[2][2], Wp[0][1],
                                     Wp[1][1], Wp[2][1], x0, x1, Wt0, Wt1, Wt2,
                                     Bt0, Bt1, Bt2, g1bf0, r2b, r2c, cnt);
  reduce2_l0_kernel<<<NB * NN, 256, 0, stream>>>(x2, g1bf0, x2bf);

  // ---- layer 0 (d0=32, d1=64, d2=64; KP=256) ----
  small_gemm<256, 32, 64, true><<<52, 256, 0, stream>>>(
      g1bf0, Bt0, bp[0][1], bp[0][2], f1a, g1bf1, uu, vv, x0, x1, Wp[0][0],
      bp[0][0], f0a);
  gemm2_kernel<64, __hip_bfloat16, true><<<NB * NN * 2, 256, 0, stream>>>(
      (const __hip_bfloat16*)x2bf, Wt0, uu, vv, f2a, r2b, cnt1, g1bf1);

  // ---- layer 1 (all dims 128; KP=512) ----
  small_gemm<512, 128, 128, true><<<52, 256, 0, stream>>>(
      g1bf1, Bt1, bp[1][1], bp[1][2], f1b, g1bf2, uu, vv, f0a, f1a, Wp[1][0],
      bp[1][0], f0b);
  gemm2_kernel<128, __hip_bfloat16, true><<<NB * NN * 2, 256, 0, stream>>>(
      f2a, Wt1, uu, vv, f2b, r2c, cnt2, g1bf2);

  // ---- layer 2 (outputs straight to d_out) ----
  small_gemm<512, 128, 128, false><<<52, 256, 0, stream>>>(
      g1bf2, Bt2, bp[2][1], bp[2][2], out_f1, nullptr, uu, vv, f0b, f1b,
      Wp[2][0], bp[2][0], out_f0);
  gemm2_kernel<128, float, false><<<NB * NN * 2, 256, 0, stream>>>(
      f2b, Wt2, uu, vv, out_f2, nullptr, nullptr, nullptr);
}

// Round 5
// 518.733 us; speedup vs baseline: 1.2105x; 1.2105x over previous
//
#include <hip/hip_runtime.h>
#include <hip/hip_bf16.h>
#include <cstdint>

#define NN 256
#define NB 4
#define OC 128

using bf16x8_t = __attribute__((ext_vector_type(8))) __bf16;
using f32x4_t  = __attribute__((ext_vector_type(4))) float;

typedef const __attribute__((address_space(1))) uint8_t* gptr1_t;
typedef __attribute__((address_space(3))) uint8_t* lptr3_t;

__device__ __forceinline__ void async_load16(const void* g, void* l) {
  __builtin_amdgcn_global_load_lds((gptr1_t)g, (lptr3_t)l, 16, 0, 0);
}

__device__ __forceinline__ float sigf(float x) {
  return 1.0f / (1.0f + __expf(-x));
}

__device__ __forceinline__ uint16_t f2bf_rne(float f) {
  uint32_t u = __float_as_uint(f);
  uint32_t r = (u + 0x7fffu + ((u >> 16) & 1u)) >> 16;
  return (uint16_t)r;
}

// ---------------------------------------------------------------------------
// prep: bf16 Wt[n][k] (gemm2 B), Bt[n][k] (small-GEMM B = [W1|Wa|Wc]),
// g1bf0 static slots (f0/f1/pad), r2b/r2c init (max=0,min=1).
// ---------------------------------------------------------------------------
__device__ __forceinline__ void emit_wt(const float* __restrict__ W2,
                                        uint16_t* __restrict__ Wt, int d1,
                                        int d2, int idx) {
  const int K = 2 * d2;
  const int nn = idx / K, k = idx - nn * K;
  const int row = (k < d2) ? (d1 + k) : (2 * d1 + d2 + (k - d2));
  Wt[idx] = f2bf_rne(W2[row * OC + nn]);
}

__device__ __forceinline__ void emit_bt(const float* __restrict__ W1,
                                        const float* __restrict__ W2,
                                        uint16_t* __restrict__ Bt, int D0,
                                        int D1, int D2, int FIN1, int KP,
                                        int idx) {
  const int n = idx / KP, k = idx - n * KP;
  float val = 0.f;
  if (n < 128) {
    if (k < FIN1) val = W1[k * OC + n];
  } else if (n < 256) {
    if (k >= D0 && k < D0 + D1) val = W2[(k - D0) * OC + (n - 128)];
  } else {
    if (k >= D0 && k < D0 + D1) val = W2[(D1 + D2 + (k - D0)) * OC + (n - 256)];
  }
  Bt[idx] = f2bf_rne(val);
}

__global__ __launch_bounds__(256) void prep_all(
    const float* __restrict__ W2_0, const float* __restrict__ W2_1,
    const float* __restrict__ W2_2, const float* __restrict__ W1_0,
    const float* __restrict__ W1_1, const float* __restrict__ W1_2,
    const float* __restrict__ x0, const float* __restrict__ x1,
    uint16_t* __restrict__ Wt0, uint16_t* __restrict__ Wt1,
    uint16_t* __restrict__ Wt2, uint16_t* __restrict__ Bt0,
    uint16_t* __restrict__ Bt1, uint16_t* __restrict__ Bt2,
    uint16_t* __restrict__ g1bf0, float* __restrict__ r2b,
    float* __restrict__ r2c) {
  int g = blockIdx.x * 256 + threadIdx.x;
  if (g < 16384) { emit_wt(W2_0, Wt0, 64, 64, g); return; }
  g -= 16384;
  if (g < 32768) { emit_wt(W2_1, Wt1, 128, 128, g); return; }
  g -= 32768;
  if (g < 32768) { emit_wt(W2_2, Wt2, 128, 128, g); return; }
  g -= 32768;
  if (g < 98304) { emit_bt(W1_0, W2_0, Bt0, 32, 64, 64, 224, 256, g); return; }
  g -= 98304;
  if (g < 196608) { emit_bt(W1_1, W2_1, Bt1, 128, 128, 128, 512, 512, g); return; }
  g -= 196608;
  if (g < 196608) { emit_bt(W1_2, W2_2, Bt2, 128, 128, 128, 512, 512, g); return; }
  g -= 196608;
  if (g < 131072) {  // g1bf0 static slots: f0[0..32) f1[32..96) pad[224..256)
    const int row = g >> 7, t = g & 127;
    uint16_t* const gp = g1bf0 + (size_t)row * 256;
    if (t < 32) gp[t] = f2bf_rne(x0[(row >> 8) * 32 + t]);
    else if (t < 96) gp[t] = f2bf_rne(x1[(size_t)row * 64 + (t - 32)]);
    else gp[128 + t] = 0;
    return;
  }
  g -= 131072;
  if (g < 262144) { r2b[g] = ((g & 255) < 128) ? 0.f : 1.f; return; }
  g -= 262144;
  if (g < 262144) { r2c[g] = ((g & 255) < 128) ? 0.f : 1.f; }
}

// ---------------------------------------------------------------------------
// reduce2 layer 0: fp32 x2 [B,n,n,64] -> bf16 x2bf (gemm2 A operand) + bf16
// max/min into g1bf0 r2-slot [96..224).
// ---------------------------------------------------------------------------
__global__ __launch_bounds__(256) void reduce2_l0_kernel(
    const float* __restrict__ x2, uint16_t* __restrict__ g1bf0,
    uint16_t* __restrict__ x2bf) {
  const int bid = blockIdx.x;            // b*256 + i
  const int i = bid & 255;
  const int tid = threadIdx.x;
  const int q = tid & 15, s = tid >> 4;  // 16 quads, 16 stripes
  const size_t rowbase = ((size_t)bid * NN) * 64 + q * 4;
  float mxA0 = 0.f, mxA1 = 0.f, mxA2 = 0.f, mxA3 = 0.f;
  float mnA0 = 1.f, mnA1 = 1.f, mnA2 = 1.f, mnA3 = 1.f;
  float mxB0 = 0.f, mxB1 = 0.f, mxB2 = 0.f, mxB3 = 0.f;
  float mnB0 = 1.f, mnB1 = 1.f, mnB2 = 1.f, mnB3 = 1.f;
#pragma unroll 2
  for (int t = 0; t < 16; t += 2) {
    const int jA = s + t * 16, jB = jA + 16;
    const float4 xa = *(const float4*)(x2 + rowbase + (size_t)jA * 64);
    const float4 xb = *(const float4*)(x2 + rowbase + (size_t)jB * 64);
    uint2 pa, pb;
    pa.x = (uint32_t)f2bf_rne(xa.x) | ((uint32_t)f2bf_rne(xa.y) << 16);
    pa.y = (uint32_t)f2bf_rne(xa.z) | ((uint32_t)f2bf_rne(xa.w) << 16);
    pb.x = (uint32_t)f2bf_rne(xb.x) | ((uint32_t)f2bf_rne(xb.y) << 16);
    pb.y = (uint32_t)f2bf_rne(xb.z) | ((uint32_t)f2bf_rne(xb.w) << 16);
    *(uint2*)(x2bf + rowbase + (size_t)jA * 64) = pa;
    *(uint2*)(x2bf + rowbase + (size_t)jB * 64) = pb;
    if (jA != i) {
      mxA0 = fmaxf(mxA0, xa.x); mxA1 = fmaxf(mxA1, xa.y);
      mxA2 = fmaxf(mxA2, xa.z); mxA3 = fmaxf(mxA3, xa.w);
      mnA0 = fminf(mnA0, xa.x); mnA1 = fminf(mnA1, xa.y);
      mnA2 = fminf(mnA2, xa.z); mnA3 = fminf(mnA3, xa.w);
    }
    if (jB != i) {
      mxB0 = fmaxf(mxB0, xb.x); mxB1 = fmaxf(mxB1, xb.y);
      mxB2 = fmaxf(mxB2, xb.z); mxB3 = fmaxf(mxB3, xb.w);
      mnB0 = fminf(mnB0, xb.x); mnB1 = fminf(mnB1, xb.y);
      mnB2 = fminf(mnB2, xb.z); mnB3 = fminf(mnB3, xb.w);
    }
  }
  float mx0 = fmaxf(mxA0, mxB0), mx1 = fmaxf(mxA1, mxB1);
  float mx2 = fmaxf(mxA2, mxB2), mx3 = fmaxf(mxA3, mxB3);
  float mn0 = fminf(mnA0, mnB0), mn1 = fminf(mnA1, mnB1);
  float mn2 = fminf(mnA2, mnB2), mn3 = fminf(mnA3, mnB3);
  __shared__ float4 smx[256], smn[256];
  smx[tid] = make_float4(mx0, mx1, mx2, mx3);
  smn[tid] = make_float4(mn0, mn1, mn2, mn3);
  __syncthreads();
  if (s == 0) {
    for (int ss = 1; ss < 16; ++ss) {
      float4 a = smx[q + ss * 16], c = smn[q + ss * 16];
      mx0 = fmaxf(mx0, a.x); mx1 = fmaxf(mx1, a.y);
      mx2 = fmaxf(mx2, a.z); mx3 = fmaxf(mx3, a.w);
      mn0 = fminf(mn0, c.x); mn1 = fminf(mn1, c.y);
      mn2 = fminf(mn2, c.z); mn3 = fminf(mn3, c.w);
    }
    uint16_t* const g = g1bf0 + (size_t)bid * 256;
    g[96 + q * 4 + 0] = f2bf_rne(mx0); g[96 + q * 4 + 1] = f2bf_rne(mx1);
    g[96 + q * 4 + 2] = f2bf_rne(mx2); g[96 + q * 4 + 3] = f2bf_rne(mx3);
    g[160 + q * 4 + 0] = f2bf_rne(mn0); g[160 + q * 4 + 1] = f2bf_rne(mn1);
    g[160 + q * 4 + 2] = f2bf_rne(mn2); g[160 + q * 4 + 3] = f2bf_rne(mn3);
  }
}

// ---------------------------------------------------------------------------
// Small fused MFMA GEMM + o0. Blocks 0..47: C[1024 x 384] = g1 @ Bt^T
// (nt=0 -> f1out=sigmoid(+b1) [+bf16 dup], nt=1 -> u=+b2, nt=2 -> vT).
// Blocks 48..51: o0 for batch b = bid-48.
// vT layout [b][c][j] so gemm2's epilogue reads v along j with float4.
// ---------------------------------------------------------------------------
template <int KP, int D0, int D1, bool DUP>
__global__ __launch_bounds__(256) void small_gemm(
    const uint16_t* __restrict__ g1, const uint16_t* __restrict__ Bt,
    const float* __restrict__ b1, const float* __restrict__ b2,
    float* __restrict__ f1out, uint16_t* __restrict__ g1next,
    float* __restrict__ u, float* __restrict__ vT,
    const float* __restrict__ f0in, const float* __restrict__ f1in,
    const float* __restrict__ W0, const float* __restrict__ b0,
    float* __restrict__ f0out) {
  constexpr int NCH = KP / 64;
  const int bid = blockIdx.x;
  const int tid = threadIdx.x;

  __shared__ __align__(16) uint8_t ldsA[8192];
  __shared__ __align__(16) uint8_t ldsB[16384];

  if (bid < 48) {
    const int mt = bid / 3, nt = bid - mt * 3;
    const int m0 = mt * 64, n0 = nt * 128;
    const int wv = tid >> 6, lane = tid & 63;
    const int l15 = lane & 15, l4 = lane >> 4;

    f32x4_t acc[4][2];
#pragma unroll
    for (int a = 0; a < 4; ++a)
#pragma unroll
      for (int q = 0; q < 2; ++q) acc[a][q] = (f32x4_t){0.f, 0.f, 0.f, 0.f};

    for (int c = 0; c < NCH; ++c) {
      const int kbg = c * 64;
#pragma unroll
      for (int t = 0; t < 2; ++t) {  // A units: id = ks*4 + mi
        const int id = wv * 2 + t;
        const int mi = id & 3, ks = id >> 2;
        async_load16(g1 + (size_t)(m0 + mi * 16 + l15) * KP + kbg + ks * 32 + l4 * 8,
                     ldsA + id * 1024);
      }
#pragma unroll
      for (int t = 0; t < 4; ++t) {  // B units: id = ks*8 + ni
        const int id = wv * 4 + t;
        const int ni = id & 7, ks = id >> 3;
        async_load16(Bt + (size_t)(n0 + ni * 16 + l15) * KP + kbg + ks * 32 + l4 * 8,
                     ldsB + id * 1024);
      }
      __syncthreads();
#pragma unroll
      for (int ks = 0; ks < 2; ++ks) {
        bf16x8_t Af[4], Bf[2];
#pragma unroll
        for (int a = 0; a < 4; ++a)
          Af[a] = *(const bf16x8_t*)(ldsA + ((ks * 4 + a) << 10) + (lane << 4));
#pragma unroll
        for (int q = 0; q < 2; ++q)
          Bf[q] = *(const bf16x8_t*)(ldsB + ((ks * 8 + wv * 2 + q) << 10) + (lane << 4));
#pragma unroll
        for (int a = 0; a < 4; ++a)
#pragma unroll
          for (int q = 0; q < 2; ++q)
            acc[a][q] = __builtin_amdgcn_mfma_f32_16x16x32_bf16(Af[a], Bf[q],
                                                                acc[a][q], 0, 0, 0);
      }
      __syncthreads();
    }

    float bias[2];
#pragma unroll
    for (int q = 0; q < 2; ++q) {
      const int cc = wv * 32 + q * 16 + l15;
      bias[q] = (nt == 0) ? b1[cc] : ((nt == 1) ? b2[cc] : 0.f);
    }
#pragma unroll
    for (int a = 0; a < 4; ++a) {
      const int rl = a * 16 + l4 * 4;
#pragma unroll
      for (int r = 0; r < 4; ++r) {
        const size_t bi = m0 + rl + r;
#pragma unroll
        for (int q = 0; q < 2; ++q) {
          const int cc = wv * 32 + q * 16 + l15;
          const float x = acc[a][q][r] + bias[q];
          if (nt == 0) {
            const float val = sigf(x);
            f1out[bi * OC + cc] = val;
            if (DUP) g1next[bi * 512 + 128 + cc] = f2bf_rne(val);
          } else if (nt == 1) {
            u[bi * OC + cc] = x;
          } else {
            const int b = (int)(bi >> 8), j = (int)(bi & 255);
            vT[((size_t)b * OC + cc) * NN + j] = x;
          }
        }
      }
    }
  } else {
    // ---- o0 for batch b ----
    constexpr int FIN0 = D0 + 2 * D1;
    constexpr int S = 256 / D1;
    const int b = bid - 48;
    float* const sm = (float*)ldsA;   // reuse LDS: g0 | smx | smn | sval
    float* const g0 = sm;             // [0..FIN0)
    float* const smx = sm + 512;
    float* const smn = sm + 768;
    float* const sval = sm + 1024;
    const int cc = tid & (D1 - 1), ss = tid / D1;
    float mx = -1e30f, mn = 1e30f;
    const float* f1b = f1in + (size_t)b * NN * D1;
    for (int j = ss; j < NN; j += S) {
      const float x = f1b[(size_t)j * D1 + cc];
      mx = fmaxf(mx, x); mn = fminf(mn, x);
    }
    smx[tid] = mx; smn[tid] = mn;
    __syncthreads();
    if (ss == 0) {
      for (int s2 = 1; s2 < S; ++s2) {
        mx = fmaxf(mx, smx[cc + s2 * D1]);
        mn = fminf(mn, smn[cc + s2 * D1]);
      }
      g0[D0 + cc] = mx;
      g0[D0 + D1 + cc] = mn;
    }
    if (tid < D0) g0[tid] = f0in[b * D0 + tid];
    __syncthreads();
    if (tid < OC) {
      float acc = b0[tid];
#pragma unroll 8
      for (int k = 0; k < FIN0; ++k) acc += g0[k] * W0[k * OC + tid];
      const float val = sigf(acc);
      f0out[b * OC + tid] = val;
      sval[tid] = val;
    }
    if (DUP) {
      __syncthreads();
      for (int idx = tid; idx < 256 * 128; idx += 256) {
        const int row = idx >> 7, c2 = idx & 127;
        g1next[((size_t)(b * 256 + row)) * 512 + c2] = f2bf_rne(sval[c2]);
      }
    }
  }
}

// ---------------------------------------------------------------------------
// conv: fp32 r2 (post gemm2 atomics) -> bf16 into g1next r2 slot [256..512).
// ---------------------------------------------------------------------------
__global__ __launch_bounds__(256) void conv_r2_kernel(
    const float* __restrict__ r2, uint16_t* __restrict__ g1next) {
  const int bi = blockIdx.x, t = threadIdx.x;
  g1next[(size_t)bi * 512 + 256 + t] = f2bf_rne(r2[(size_t)bi * 256 + t]);
}

// ---------------------------------------------------------------------------
// Big order-2 GEMM. Block = (b, i, j-tile of 128): output 128 rows x 128 ch.
//   acc[j,c] = sum_k f2[b,i,j,k]*Wb[k,c] + sum_k f2[b,j,i,k]*Wd[k,c]
//   out = sigmoid(acc + u[b,i,c] + vT[b][c][j])
// vT is v transposed so the epilogue reads 4 j-consecutive floats per float4.
// bf16-out path: LDS-staged coalesced stores + fused next-layer reduce2
// (device atomics on uint, exclude j==i; values in (0,1)).
// ---------------------------------------------------------------------------
template <int D2, typename OUT_T, bool REDUCE>
__global__ __launch_bounds__(256, 4) void gemm2_kernel(
    const __hip_bfloat16* __restrict__ f2, const uint16_t* __restrict__ Wt,
    const float* __restrict__ u, const float* __restrict__ vT,
    OUT_T* __restrict__ out, float* __restrict__ r2n) {
  constexpr int K = 2 * D2;
  constexpr int NCH = K / 64;
  constexpr bool BF16OUT = (sizeof(OUT_T) == 2);
  constexpr int LDSB = BF16OUT ? (128 * 272) : 32768;
  const int bid = blockIdx.x;
  const int jt = bid & 1, i = (bid >> 1) & 255, b = bid >> 9;
  const int j0 = jt * 128;
  const int tid = threadIdx.x;
  const int wv = tid >> 6, lane = tid & 63;
  const int wr = wv >> 1, wc = wv & 1;
  const int l15 = lane & 15, l4 = lane >> 4;

  __shared__ __align__(16) uint8_t lds[LDSB];
  __shared__ unsigned smax[128], smin[128];
  uint8_t* const ldsA = lds;
  uint8_t* const ldsW = lds + 16384;

  const __hip_bfloat16* A1 = f2 + ((size_t)(b * NN + i) * NN + j0) * D2;
  const __hip_bfloat16* A2 = f2 + ((size_t)(b * NN + j0) * NN + i) * D2;

  f32x4_t acc[4][4];
#pragma unroll
  for (int a = 0; a < 4; ++a)
#pragma unroll
    for (int q = 0; q < 4; ++q) acc[a][q] = (f32x4_t){0.f, 0.f, 0.f, 0.f};

  for (int c = 0; c < NCH; ++c) {
    const int kbg = c * 64;
    const bool second = (kbg >= D2);
    const __hip_bfloat16* Ab = second ? A2 : A1;
    const size_t rstride = second ? (size_t)NN * D2 : (size_t)D2;
    const int kbase = second ? (kbg - D2) : kbg;
#pragma unroll
    for (int q = 0; q < 4; ++q) {
      const int id = wv * 4 + q;
      const int mi = id & 7, ks = id >> 3;
      const int row = mi * 16 + l15;
      const int kk = ks * 32 + l4 * 8;
      async_load16(Ab + (size_t)row * rstride + kbase + kk, ldsA + id * 1024);
    }
#pragma unroll
    for (int q = 0; q < 4; ++q) {
      const int id = wv * 4 + q;
      const int ni = id & 7, ks = id >> 3;
      const int nn2 = ni * 16 + l15;
      const int kk = ks * 32 + l4 * 8;
      async_load16(Wt + (size_t)nn2 * K + kbg + kk, ldsW + id * 1024);
    }
    __syncthreads();
#pragma unroll
    for (int ks = 0; ks < 2; ++ks) {
      bf16x8_t Af[4], Bf[4];
#pragma unroll
      for (int a = 0; a < 4; ++a)
        Af[a] = *(const bf16x8_t*)(ldsA + ((ks * 8 + wr * 4 + a) << 10) + (lane << 4));
#pragma unroll
      for (int q = 0; q < 4; ++q)
        Bf[q] = *(const bf16x8_t*)(ldsW + ((ks * 8 + wc * 4 + q) << 10) + (lane << 4));
#pragma unroll
      for (int a = 0; a < 4; ++a)
#pragma unroll
        for (int q = 0; q < 4; ++q)
          acc[a][q] = __builtin_amdgcn_mfma_f32_16x16x32_bf16(Af[a], Bf[q],
                                                              acc[a][q], 0, 0, 0);
    }
    __syncthreads();
  }

  const size_t bi2 = (size_t)(b * NN + i);
  float uval[4];
#pragma unroll
  for (int q = 0; q < 4; ++q) uval[q] = u[bi2 * OC + wc * 64 + q * 16 + l15];
  const size_t obase = (bi2 * NN + j0) * OC;
  const float* const vTb = vT + (size_t)b * OC * NN;

  if (BF16OUT) {
    if (REDUCE && tid < 128) { smax[tid] = 0u; smin[tid] = 0x3f800000u; }
    __syncthreads();
    float lmx[4] = {0.f, 0.f, 0.f, 0.f};
    float lmn[4] = {1.f, 1.f, 1.f, 1.f};
#pragma unroll
    for (int a = 0; a < 4; ++a) {
      const int rowb = wr * 64 + a * 16 + l4 * 4;
      const int jg = j0 + rowb;
#pragma unroll
      for (int q = 0; q < 4; ++q) {
        const int col = wc * 64 + q * 16 + l15;
        const float4 vq = *(const float4*)(vTb + (size_t)col * NN + jg);
#pragma unroll
        for (int r = 0; r < 4; ++r) {
          const int j = rowb + r;
          const float x = acc[a][q][r] + uval[q] + ((const float*)&vq)[r];
          const float sg = sigf(x);
          *(uint16_t*)(lds + j * 272 + col * 2) = f2bf_rne(sg);
          if (REDUCE && (jg + r) != i) {
            lmx[q] = fmaxf(lmx[q], sg);
            lmn[q] = fminf(lmn[q], sg);
          }
        }
      }
    }
    if (REDUCE) {
#pragma unroll
      for (int q = 0; q < 4; ++q) {
        const int col = wc * 64 + q * 16 + l15;
        atomicMax(&smax[col], __float_as_uint(lmx[q]));
        atomicMin(&smin[col], __float_as_uint(lmn[q]));
      }
    }
    __syncthreads();
    uint16_t* const outp = (uint16_t*)out;
#pragma unroll
    for (int ci = 0; ci < 8; ++ci) {
      const int chunk = ci * 256 + tid;
      const int row = chunk >> 4, off = chunk & 15;
      const uint4 val = *(const uint4*)(lds + row * 272 + off * 16);
      *(uint4*)(outp + obase + (size_t)row * OC + off * 8) = val;
    }
    if (REDUCE && tid < 128) {
      unsigned* const r2u = (unsigned*)r2n;
      atomicMax(&r2u[bi2 * 256 + tid], smax[tid]);
      atomicMin(&r2u[bi2 * 256 + 128 + tid], smin[tid]);
    }
  } else {
    float* const outp = (float*)out;
#pragma unroll
    for (int a = 0; a < 4; ++a) {
      const int rowb = wr * 64 + a * 16 + l4 * 4;
      const int jg = j0 + rowb;
#pragma unroll
      for (int q = 0; q < 4; ++q) {
        const int col = wc * 64 + q * 16 + l15;
        const float4 vq = *(const float4*)(vTb + (size_t)col * NN + jg);
#pragma unroll
        for (int r = 0; r < 4; ++r) {
          const int j = rowb + r;
          const float x = acc[a][q][r] + uval[q] + ((const float*)&vq)[r];
          outp[obase + (size_t)j * OC + col] = sigf(x);
        }
      }
    }
  }
}

// ---------------------------------------------------------------------------
extern "C" void kernel_launch(void* const* d_in, const int* in_sizes, int n_in,
                              void* d_out, int out_size, void* d_ws,
                              size_t ws_size, hipStream_t stream) {
  const float* x0 = (const float*)d_in[0];
  const float* x1 = (const float*)d_in[1];
  const float* x2 = (const float*)d_in[2];
  const float *Wp[3][3], *bp[3][3];
  for (int l = 0; l < 3; ++l)
    for (int o = 0; o < 3; ++o) {
      Wp[l][o] = (const float*)d_in[3 + l * 6 + o * 2];
      bp[l][o] = (const float*)d_in[3 + l * 6 + o * 2 + 1];
    }

  const size_t F2E = (size_t)NB * NN * NN * OC;
  const size_t X2E = (size_t)NB * NN * NN * 64;

  uint8_t* ws = (uint8_t*)d_ws;
  size_t off = 0;
  auto carve = [&](size_t bytes) -> uint8_t* {
    uint8_t* p = ws + off;
    off += (bytes + 255) & ~(size_t)255;
    return p;
  };
  float* f0a = (float*)carve((size_t)NB * OC * 4);
  float* f0b = (float*)carve((size_t)NB * OC * 4);
  float* f1a = (float*)carve((size_t)NB * NN * OC * 4);
  float* f1b = (float*)carve((size_t)NB * NN * OC * 4);
  float* r2b = (float*)carve((size_t)NB * NN * 256 * 4);
  float* r2c = (float*)carve((size_t)NB * NN * 256 * 4);
  float* uu  = (float*)carve((size_t)NB * NN * OC * 4);
  float* vT  = (float*)carve((size_t)NB * OC * NN * 4);
  uint16_t* Wt0 = (uint16_t*)carve((size_t)OC * 128 * 2);
  uint16_t* Wt1 = (uint16_t*)carve((size_t)OC * 256 * 2);
  uint16_t* Wt2 = (uint16_t*)carve((size_t)OC * 256 * 2);
  uint16_t* Bt0 = (uint16_t*)carve((size_t)384 * 256 * 2);
  uint16_t* Bt1 = (uint16_t*)carve((size_t)384 * 512 * 2);
  uint16_t* Bt2 = (uint16_t*)carve((size_t)384 * 512 * 2);
  uint16_t* g1bf0 = (uint16_t*)carve((size_t)NB * NN * 256 * 2);
  uint16_t* g1bf1 = (uint16_t*)carve((size_t)NB * NN * 512 * 2);
  uint16_t* g1bf2 = (uint16_t*)carve((size_t)NB * NN * 512 * 2);
  __hip_bfloat16* f2a = (__hip_bfloat16*)carve(F2E * 2);

  __hip_bfloat16* f2b;
  uint16_t* x2bf;
  if (ws_size >= off + F2E * 2) {
    f2b = (__hip_bfloat16*)carve(F2E * 2);
    x2bf = (uint16_t*)f2b;  // aliases f2b; dead before f2b becomes live
  } else {
    f2b = (__hip_bfloat16*)d_in[2];  // x2 fully consumed in layer 0
    x2bf = (uint16_t*)carve(X2E * 2);
  }

  float* out_f0 = (float*)d_out;
  float* out_f1 = out_f0 + (size_t)NB * OC;
  float* out_f2 = out_f1 + (size_t)NB * NN * OC;

  prep_all<<<4800, 256, 0, stream>>>(Wp[0][2], Wp[1][2], Wp[2][2], Wp[0][1],
                                     Wp[1][1], Wp[2][1], x0, x1, Wt0, Wt1, Wt2,
                                     Bt0, Bt1, Bt2, g1bf0, r2b, r2c);
  reduce2_l0_kernel<<<NB * NN, 256, 0, stream>>>(x2, g1bf0, x2bf);

  // ---- layer 0 (d0=32, d1=64, d2=64; KP=256) ----
  small_gemm<256, 32, 64, true><<<52, 256, 0, stream>>>(
      g1bf0, Bt0, bp[0][1], bp[0][2], f1a, g1bf1, uu, vT, x0, x1, Wp[0][0],
      bp[0][0], f0a);
  gemm2_kernel<64, __hip_bfloat16, true><<<NB * NN * 2, 256, 0, stream>>>(
      (const __hip_bfloat16*)x2bf, Wt0, uu, vT, f2a, r2b);
  conv_r2_kernel<<<NB * NN, 256, 0, stream>>>(r2b, g1bf1);

  // ---- layer 1 (all dims 128; KP=512) ----
  small_gemm<512, 128, 128, true><<<52, 256, 0, stream>>>(
      g1bf1, Bt1, bp[1][1], bp[1][2], f1b, g1bf2, uu, vT, f0a, f1a, Wp[1][0],
      bp[1][0], f0b);
  gemm2_kernel<128, __hip_bfloat16, true><<<NB * NN * 2, 256, 0, stream>>>(
      f2a, Wt1, uu, vT, f2b, r2c);
  conv_r2_kernel<<<NB * NN, 256, 0, stream>>>(r2c, g1bf2);

  // ---- layer 2 (outputs straight to d_out) ----
  small_gemm<512, 128, 128, false><<<52, 256, 0, stream>>>(
      g1bf2, Bt2, bp[2][1], bp[2][2], out_f1, nullptr, uu, vT, f0b, f1b,
      Wp[2][0], bp[2][0], out_f0);
  gemm2_kernel<128, float, false><<<NB * NN * 2, 256, 0, stream>>>(
      f2b, Wt2, uu, vT, out_f2, nullptr);
}